// Round 1
// baseline (397.748 us; speedup 1.0000x reference)
//
#include <hip/hip_runtime.h>
#include <hip/hip_bf16.h>

// KAN layer as one bf16 GEMM: out[8192,512] = A[8192,7168] @ W[512,7168]^T + b
//   A = [ silu(x) (512 cols) | b_splines(x) (512*13 cols) ]   built by kan_prep
//   W = [ base_w | spline_w.reshape(512, 6656) ]              built by kan_wconv

#define BATCH   8192
#define IN_F    512
#define N_OUT   512
#define NG      13            // GRID_SIZE + K
#define K_TOT   7168          // 512 + 512*13
#define BM      128
#define BN      128
#define BK      64
#define KSPLIT  4
#define KPB     (K_TOT / KSPLIT)   // 1792 = 28 * BK

typedef short short8 __attribute__((ext_vector_type(8)));
typedef float floatx4 __attribute__((ext_vector_type(4)));

__device__ __forceinline__ unsigned short f2bf(float f) {
    union { float f; unsigned u; } v; v.f = f;
    unsigned r = v.u + 0x7FFFu + ((v.u >> 16) & 1u);   // RNE
    return (unsigned short)(r >> 16);
}

// ---------------- W conversion: [512][7168] bf16 ----------------
__global__ void kan_wconv(const float* __restrict__ base_w,
                          const float* __restrict__ spline_w,
                          unsigned short* __restrict__ Wb) {
    int c = blockIdx.x * 256 + threadIdx.x;   // 0..7167  (grid.x = 28)
    int o = blockIdx.y;                        // 0..511
    float v = (c < IN_F) ? base_w[o * IN_F + c]
                         : spline_w[(long)o * (IN_F * NG) + (c - IN_F)];
    Wb[(long)o * K_TOT + c] = f2bf(v);
}

// ---------------- A construction: silu + cubic B-spline bases ----------------
__global__ void kan_prep(const float* __restrict__ X,
                         unsigned short* __restrict__ A,
                         int row0, int nrows) {
    int idx = blockIdx.x * 256 + threadIdx.x;
    if (idx >= nrows * IN_F) return;
    int b = idx >> 9;          // row within chunk
    int i = idx & 511;
    float x = X[(long)(row0 + b) * IN_F + i];

    unsigned short* arow = A + (long)b * K_TOT;
    // silu
    float s = x / (1.0f + expf(-x));
    arow[i] = f2bf(s);

    // knots t_j = -3.2 + 0.4j, j=0..16  (uniform)
    float bb[16];
#pragma unroll
    for (int j = 0; j < 16; j++) {
        float t0 = -3.2f + 0.4f * j;
        bb[j] = (x >= t0 && x < t0 + 0.4f) ? 1.0f : 0.0f;
    }
    const float inv1 = 1.0f / (0.4f + 1e-8f);
    const float inv2 = 1.0f / (0.8f + 1e-8f);
    const float inv3 = 1.0f / (1.2f + 1e-8f);
#pragma unroll
    for (int j = 0; j < 15; j++) {   // p = 1: t_{j+2}-x over denom 0.4
        float tj = -3.2f + 0.4f * j;
        bb[j] = (x - tj) * inv1 * bb[j] + ((tj + 0.8f) - x) * inv1 * bb[j + 1];
    }
#pragma unroll
    for (int j = 0; j < 14; j++) {   // p = 2: denom 0.8
        float tj = -3.2f + 0.4f * j;
        bb[j] = (x - tj) * inv2 * bb[j] + ((tj + 1.2f) - x) * inv2 * bb[j + 1];
    }
#pragma unroll
    for (int j = 0; j < 13; j++) {   // p = 3: denom 1.2
        float tj = -3.2f + 0.4f * j;
        bb[j] = (x - tj) * inv3 * bb[j] + ((tj + 1.6f) - x) * inv3 * bb[j + 1];
    }
    unsigned short* brow = arow + IN_F + i * NG;
#pragma unroll
    for (int g = 0; g < NG; g++) brow[g] = f2bf(bb[g]);
}

// ---------------- GEMM: C += A @ W^T (bf16 MFMA, split-K atomic) ----------------
__global__ __launch_bounds__(256)
void kan_gemm(const unsigned short* __restrict__ A,   // [nrows][7168] bf16 bits
              const unsigned short* __restrict__ Wb,  // [512][7168]  bf16 bits
              const float* __restrict__ bias,         // [512]
              float* __restrict__ out,                // [8192][512] fp32 (zeroed)
              int row0) {
    __shared__ unsigned short As[BM][72];   // pad 64->72: 2-way bank alias only
    __shared__ unsigned short Bs[BN][72];

    const int tid  = threadIdx.x;
    const int lane = tid & 63;
    const int wave = tid >> 6;
    const int wm   = wave >> 1;      // 0..1
    const int wn   = wave & 1;       // 0..1
    const int quad = lane >> 4;      // 0..3
    const int l16  = lane & 15;

    const int m0 = blockIdx.x * BM;          // within chunk
    const int n0 = blockIdx.y * BN;
    const int ks = blockIdx.z;
    const long kbase = (long)ks * KPB;

    // staging decode: per issue q, row = q*32 + rr, 16B chunk c = tid&7
    const int rr = tid >> 3;                 // 0..31
    const int c8 = (tid & 7) * 8;            // element offset in row

    const unsigned short* pA = A  + (long)(m0 + rr) * K_TOT + kbase + c8;
    const unsigned short* pB = Wb + (long)(n0 + rr) * K_TOT + kbase + c8;

    floatx4 acc[4][4];
#pragma unroll
    for (int i = 0; i < 4; i++)
#pragma unroll
        for (int j = 0; j < 4; j++) acc[i][j] = (floatx4){0.f, 0.f, 0.f, 0.f};

    float4 ra[4], rb[4];
#pragma unroll
    for (int q = 0; q < 4; q++) {
        ra[q] = *(const float4*)(pA + (long)q * 32 * K_TOT);
        rb[q] = *(const float4*)(pB + (long)q * 32 * K_TOT);
    }

    for (int kk = 0; kk < KPB; kk += BK) {
        __syncthreads();                    // prior compute done before overwrite
#pragma unroll
        for (int q = 0; q < 4; q++) {
            *(float4*)&As[q * 32 + rr][c8] = ra[q];
            *(float4*)&Bs[q * 32 + rr][c8] = rb[q];
        }
        __syncthreads();

        pA += BK; pB += BK;
        if (kk + BK < KPB) {                // prefetch next tile into regs
#pragma unroll
            for (int q = 0; q < 4; q++) {
                ra[q] = *(const float4*)(pA + (long)q * 32 * K_TOT);
                rb[q] = *(const float4*)(pB + (long)q * 32 * K_TOT);
            }
        }

#pragma unroll
        for (int s = 0; s < 2; s++) {       // two k=32 MFMA steps per BK=64
            short8 af[4], bfr[4];
#pragma unroll
            for (int t = 0; t < 4; t++)
                af[t] = *(const short8*)&As[wm * 64 + t * 16 + l16][s * 32 + quad * 8];
#pragma unroll
            for (int t = 0; t < 4; t++)
                bfr[t] = *(const short8*)&Bs[wn * 64 + t * 16 + l16][s * 32 + quad * 8];
#pragma unroll
            for (int i = 0; i < 4; i++)
#pragma unroll
                for (int j = 0; j < 4; j++)
                    acc[i][j] = __builtin_amdgcn_mfma_f32_16x16x32_bf16(
                        af[i], bfr[j], acc[i][j], 0, 0, 0);
        }
    }

    // epilogue: C/D layout col=lane&15, row=quad*4+reg
#pragma unroll
    for (int i = 0; i < 4; i++) {
        int grow0 = row0 + m0 + wm * 64 + i * 16 + quad * 4;
#pragma unroll
        for (int j = 0; j < 4; j++) {
            int col = n0 + wn * 64 + j * 16 + l16;
            float bv = (ks == 0) ? bias[col] : 0.0f;
#pragma unroll
            for (int r = 0; r < 4; r++)
                atomicAdd(out + (long)(grow0 + r) * N_OUT + col, acc[i][j][r] + bv);
        }
    }
}

extern "C" void kernel_launch(void* const* d_in, const int* in_sizes, int n_in,
                              void* d_out, int out_size, void* d_ws, size_t ws_size,
                              hipStream_t stream) {
    const float* x        = (const float*)d_in[0];
    const float* base_w   = (const float*)d_in[1];
    const float* base_b   = (const float*)d_in[2];
    const float* spline_w = (const float*)d_in[3];
    float* out = (float*)d_out;

    unsigned short* Wb = (unsigned short*)d_ws;            // 512*7168 bf16
    const size_t wbytes = (size_t)N_OUT * K_TOT * 2;       // 7.34 MB
    unsigned short* Abuf = Wb + (size_t)N_OUT * K_TOT;

    // M-chunking so the A buffer fits whatever ws we were given
    size_t avail = (ws_size > wbytes) ? (ws_size - wbytes) : 0;
    long max_rows = (long)(avail / ((size_t)K_TOT * 2));
    int chunk = BATCH;
    while (chunk > 128 && chunk > max_rows) chunk >>= 1;

    hipMemsetAsync(d_out, 0, (size_t)BATCH * N_OUT * sizeof(float), stream);
    kan_wconv<<<dim3(K_TOT / 256, N_OUT), 256, 0, stream>>>(base_w, spline_w, Wb);

    for (int row0 = 0; row0 < BATCH; row0 += chunk) {
        int nthr = chunk * IN_F;
        kan_prep<<<dim3((nthr + 255) / 256), 256, 0, stream>>>(x, Abuf, row0, chunk);
        kan_gemm<<<dim3(chunk / BM, N_OUT / BN, KSPLIT), 256, 0, stream>>>(
            Abuf, Wb, base_b, out, row0);
    }
}